// Round 4
// baseline (142.833 us; speedup 1.0000x reference)
//
#include <hip/hip_runtime.h>

#define N_TOK 8192

typedef _Float16 f16x8 __attribute__((ext_vector_type(8)));
typedef _Float16 f16x4 __attribute__((ext_vector_type(4)));
typedef float    f32x4 __attribute__((ext_vector_type(4)));

__device__ __forceinline__ f32x4 mfma_k32(f16x8 a, f16x8 b, f32x4 c) {
  return __builtin_amdgcn_mfma_f32_16x16x32_f16(a, b, c, 0, 0, 0);
}
__device__ __forceinline__ f32x4 mfma_k16(f16x4 a, f16x4 b, f32x4 c) {
  // NOTE: legacy spelling, no underscore before f16 (gfx908-era opcode name).
  return __builtin_amdgcn_mfma_f32_16x16x16f16(a, b, c, 0, 0, 0);
}

// QSCALE^2 = log2(e)/sqrt(32); fold softmax scale + ln->log2 into q so
// s2[n,m] = qe_n . qe_m is directly the exp2 exponent.
#define QSCALE 0.50500977f

// ---------------------------------------------------------------------------
// Kernel A: qe[n][32] = fp16((W x + bias) * QSCALE); vh = fp16(x)
// blocks 0..127: LDS-tiled coalesced projection, 64 n-cols per block.
// blocks 128..639: vh convert, float4-vectorized.
// ---------------------------------------------------------------------------
__global__ __launch_bounds__(256) void prep_kernel(
    const float* __restrict__ x, const float* __restrict__ W,
    const float* __restrict__ bias, _Float16* __restrict__ qe,
    _Float16* __restrict__ vh) {
  int blk = blockIdx.x, t = threadIdx.x;
  if (blk < 128) {
    __shared__ float Wl[32 * 65];   // pad 65: distinct banks across o
    __shared__ float xs[64 * 72];   // [c][n0..n0+63], pad 72
    for (int i = t; i < 2048; i += 256) Wl[(i >> 6) * 65 + (i & 63)] = W[i];
    int n0 = blk * 64;
#pragma unroll
    for (int rr = 0; rr < 16; ++rr) {  // wave reads one full 256B row at a time
      int c = rr * 4 + (t >> 6);
      xs[c * 72 + (t & 63)] = x[c * N_TOK + n0 + (t & 63)];
    }
    __syncthreads();
    int o = t & 31, ns = t >> 5;  // thread: output channel o, 8 n (stride 8)
    float acc[8];
    float bv = bias[o];
#pragma unroll
    for (int i = 0; i < 8; ++i) acc[i] = bv;
    for (int c = 0; c < 64; ++c) {
      float wv = Wl[o * 65 + c];
#pragma unroll
      for (int i = 0; i < 8; ++i)
        acc[i] = fmaf(wv, xs[c * 72 + ns + i * 8], acc[i]);
    }
#pragma unroll
    for (int i = 0; i < 8; ++i)
      qe[(n0 + ns + i * 8) * 32 + o] = (_Float16)(acc[i] * QSCALE);
  } else {
    int i4 = (blk - 128) * 256 + t;  // 512 blocks cover 128K float4s
    f32x4 v = ((const f32x4*)x)[i4];
    f16x4 h;
#pragma unroll
    for (int j = 0; j < 4; ++j) h[j] = (_Float16)v[j];
    *(f16x4*)(vh + i4 * 4) = h;
  }
}

// ---------------------------------------------------------------------------
// Kernel B (pass 1): Bn[n] = log2( sum_m exp2(qe_n . qe_m) )
// 256 blocks x 512 thr; block = 32 rows (2 A-frags); 8 waves split m 8-way.
// 2x2 MFMA tiles -> 4 independent MFMA+exp chains; wrap-around prefetch.
// ---------------------------------------------------------------------------
__global__ __launch_bounds__(512) void pass1_kernel(
    const _Float16* __restrict__ qe, float* __restrict__ Bn) {
  __shared__ float Lp[8][32];
  int t = threadIdx.x;
  int w = t >> 6, lane = t & 63, quad = lane >> 4, l15 = lane & 15;
  int n0 = blockIdx.x * 32;
  f16x8 af0 = *(const f16x8*)(qe + (n0 + l15) * 32 + quad * 8);
  f16x8 af1 = *(const f16x8*)(qe + (n0 + 16 + l15) * 32 + quad * 8);
  const _Float16* qb = qe + (w * 1024 + l15) * 32 + quad * 8;
  f16x8 pb0 = *(const f16x8*)(qb);        // prefetched B tiles
  f16x8 pb1 = *(const f16x8*)(qb + 512);  // +16 rows
  f32x4 a00 = {0.f, 0.f, 0.f, 0.f}, a01 = a00, a10 = a00, a11 = a00;
  for (int mt = 0; mt < 32; ++mt) {
    f16x8 b0 = pb0, b1 = pb1;
    int nx = ((mt + 1) & 31) * 1024;  // wrap: always-valid prefetch, no branch
    pb0 = *(const f16x8*)(qb + nx);
    pb1 = *(const f16x8*)(qb + nx + 512);
    f32x4 z = {0.f, 0.f, 0.f, 0.f};
    f32x4 s00 = mfma_k32(af0, b0, z);
    f32x4 s01 = mfma_k32(af0, b1, z);
    f32x4 s10 = mfma_k32(af1, b0, z);
    f32x4 s11 = mfma_k32(af1, b1, z);
#pragma unroll
    for (int r = 0; r < 4; ++r) {
      a00[r] += __builtin_amdgcn_exp2f(s00[r]);
      a01[r] += __builtin_amdgcn_exp2f(s01[r]);
      a10[r] += __builtin_amdgcn_exp2f(s10[r]);
      a11[r] += __builtin_amdgcn_exp2f(s11[r]);
    }
  }
  f32x4 sums0 = a00 + a01;  // rows n0 + quad*4 + r
  f32x4 sums1 = a10 + a11;  // rows n0 + 16 + quad*4 + r
#pragma unroll
  for (int r = 0; r < 4; ++r) {
#pragma unroll
    for (int mask = 1; mask < 16; mask <<= 1) {
      sums0[r] += __shfl_xor(sums0[r], mask, 64);
      sums1[r] += __shfl_xor(sums1[r], mask, 64);
    }
  }
  if (l15 == 0) {
    *(f32x4*)&Lp[w][quad * 4] = sums0;
    *(f32x4*)&Lp[w][16 + quad * 4] = sums1;
  }
  __syncthreads();
  if (t < 32) {
    float L = 0.f;
#pragma unroll
    for (int ww = 0; ww < 8; ++ww) L += Lp[ww][t];
    Bn[n0 + t] = __builtin_amdgcn_logf(L);  // v_log_f32 = log2
  }
}

// ---------------------------------------------------------------------------
// Kernel C (pass 2): out[c,m] = sum_n vh[c,n] * exp2(qe_n.qe_m - Bn[n]) + x
// 256 blocks x 512 thr (8 waves); block = 32 m-cols, all 64 c; waves split n
// 8-way (1024 each). NO LDS in the hot loop: the exp2'd S fragment in C/D
// layout (row=quad*4+r, col=l15) IS a valid 16x16x16 B-fragment
// (k=quad*4+j, col=l15) after f16 packing — PV uses K=16 MFMAs directly.
// ---------------------------------------------------------------------------
__global__ __launch_bounds__(512, 4) void pass2_kernel(
    const _Float16* __restrict__ qe, const _Float16* __restrict__ vh,
    const float* __restrict__ Bn, const float* __restrict__ x,
    float* __restrict__ out) {
  __shared__ float Ot[4 * 64 * 33];  // combine: [4 sets][64 c][33]
  int t = threadIdx.x;
  int w = t >> 6, lane = t & 63, quad = lane >> 4, l15 = lane & 15;
  int m0 = blockIdx.x * 32;

  // B frags for the S matmul: cols m0..m0+31 (fixed for whole kernel)
  f16x8 bm0 = *(const f16x8*)(qe + (m0 + l15) * 32 + quad * 8);
  f16x8 bm1 = *(const f16x8*)(qe + (m0 + 16 + l15) * 32 + quad * 8);

  int base = w * 1024;  // this wave's n-slice
  const _Float16* qa = qe + (base + l15) * 32 + quad * 8;
  const float* bnb = Bn + base + quad * 4;
  const _Float16* vb = vh + l15 * N_TOK + base + quad * 4;

  f32x4 acc[4][2];
#pragma unroll
  for (int ct = 0; ct < 4; ++ct)
#pragma unroll
    for (int mt = 0; mt < 2; ++mt) acc[ct][mt] = f32x4{0.f, 0.f, 0.f, 0.f};

  // ping-pong prefetch of the chain-head loads (an rows + Bn)
  f16x8 anb[2][2];
  f32x4 Bqb[2][2];
  anb[0][0] = *(const f16x8*)(qa);
  anb[0][1] = *(const f16x8*)(qa + 512);
  Bqb[0][0] = *(const f32x4*)(bnb);
  Bqb[0][1] = *(const f32x4*)(bnb + 16);

#pragma unroll 2
  for (int ch = 0; ch < 32; ++ch) {
    int cur = ch & 1, nxt = cur ^ 1;
    int rnx = ((ch + 1) & 31) * 32;  // wrap: always-valid prefetch
    anb[nxt][0] = *(const f16x8*)(qa + rnx * 32);
    anb[nxt][1] = *(const f16x8*)(qa + rnx * 32 + 512);
    Bqb[nxt][0] = *(const f32x4*)(bnb + rnx);
    Bqb[nxt][1] = *(const f32x4*)(bnb + rnx + 16);

    int rc = ch * 32;
    f16x4 av[4][2];  // A frags for PV: A[c=l15][k=quad*4+j]
#pragma unroll
    for (int ct = 0; ct < 4; ++ct)
#pragma unroll
      for (int nt = 0; nt < 2; ++nt)
        av[ct][nt] = *(const f16x4*)(vb + ct * 16 * N_TOK + rc + nt * 16);

    f32x4 z = {0.f, 0.f, 0.f, 0.f};
    f32x4 s00 = mfma_k32(anb[cur][0], bm0, z);
    f32x4 s01 = mfma_k32(anb[cur][0], bm1, z);
    f32x4 s10 = mfma_k32(anb[cur][1], bm0, z);
    f32x4 s11 = mfma_k32(anb[cur][1], bm1, z);
    f16x4 p00, p01, p10, p11;
#pragma unroll
    for (int r = 0; r < 4; ++r) {
      p00[r] = (_Float16)__builtin_amdgcn_exp2f(s00[r] - Bqb[cur][0][r]);
      p01[r] = (_Float16)__builtin_amdgcn_exp2f(s01[r] - Bqb[cur][0][r]);
      p10[r] = (_Float16)__builtin_amdgcn_exp2f(s10[r] - Bqb[cur][1][r]);
      p11[r] = (_Float16)__builtin_amdgcn_exp2f(s11[r] - Bqb[cur][1][r]);
    }
    // PV: p(nt)(mt) is directly the B-frag; av[ct][nt] the A-frag.
#pragma unroll
    for (int ct = 0; ct < 4; ++ct) {
      acc[ct][0] = mfma_k16(av[ct][0], p00, acc[ct][0]);
      acc[ct][1] = mfma_k16(av[ct][0], p01, acc[ct][1]);
      acc[ct][0] = mfma_k16(av[ct][1], p10, acc[ct][0]);
      acc[ct][1] = mfma_k16(av[ct][1], p11, acc[ct][1]);
    }
  }

  // Combine partials across the 8 n-segments (8 -> 4 -> 1).
  if (w < 4) {
#pragma unroll
    for (int ct = 0; ct < 4; ++ct)
#pragma unroll
      for (int mt = 0; mt < 2; ++mt)
#pragma unroll
        for (int r = 0; r < 4; ++r)
          Ot[(w * 64 + ct * 16 + quad * 4 + r) * 33 + mt * 16 + l15] =
              acc[ct][mt][r];
  }
  __syncthreads();
  if (w >= 4) {
#pragma unroll
    for (int ct = 0; ct < 4; ++ct)
#pragma unroll
      for (int mt = 0; mt < 2; ++mt)
#pragma unroll
        for (int r = 0; r < 4; ++r)
          Ot[((w - 4) * 64 + ct * 16 + quad * 4 + r) * 33 + mt * 16 + l15] +=
              acc[ct][mt][r];
  }
  __syncthreads();
  // 2048 outputs, 512 threads -> 4 each; m consecutive across lanes.
  for (int idx = t; idx < 2048; idx += 512) {
    int cc = idx >> 5, m = idx & 31;
    float v = 0.f;
#pragma unroll
    for (int s = 0; s < 4; ++s) v += Ot[(s * 64 + cc) * 33 + m];
    out[cc * N_TOK + m0 + m] = v + x[cc * N_TOK + m0 + m];
  }
}

// ---------------------------------------------------------------------------
extern "C" void kernel_launch(void* const* d_in, const int* in_sizes, int n_in,
                              void* d_out, int out_size, void* d_ws,
                              size_t ws_size, hipStream_t stream) {
  const float* x = (const float*)d_in[0];     // [64][8192]
  const float* W = (const float*)d_in[1];     // [32][64]
  const float* bias = (const float*)d_in[2];  // [32]
  float* out = (float*)d_out;                 // [64][8192]

  char* ws = (char*)d_ws;
  _Float16* qe = (_Float16*)ws;                 // 8192*32*2 = 512 KB
  _Float16* vh = (_Float16*)(ws + 524288);      // 64*8192*2 = 1 MB
  float* Bn = (float*)(ws + 524288 + 1048576);  // 8192*4 = 32 KB

  prep_kernel<<<640, 256, 0, stream>>>(x, W, bias, qe, vh);
  pass1_kernel<<<256, 512, 0, stream>>>(qe, Bn);
  pass2_kernel<<<256, 512, 0, stream>>>(qe, vh, Bn, x, out);
}